// Round 7
// baseline (312.103 us; speedup 1.0000x reference)
//
#include <hip/hip_runtime.h>
#include <cstdint>
#include <cstddef>

// DeformablePoseViT: bs=16, lq=1000, d=256, nh=8, L=4, P=4, dh=32
// value pyramid: (80,80),(40,40),(20,20),(10,10) -> lv=8500
//
// Pipeline:
//  0) wconv : Wt_* = bf16(W_*^T) [N][256] for the 4 weight matrices
//  1) gemm_pers<16,16,true> : vbf = bf16(value @ W_val + b_val) [136000x256]
//  2) gemm_pers<4,16,false> : Lgo = query @ W_off + b_off       [16000x256]
//  3) gemm_pers<4, 8,false> : Lga = query @ W_attn + b_attn     [16000x128]
//  4) sample_fused : softmax+locs (in-block) + bilinear gather -> outs
//  5) gemm_pers<4,16,false> : d_out = outs @ W_out + b_out      [16000x256]
//
// gemm_pers: PERSISTENT B-resident streaming GEMM. Full Wt (N x 256 bf16,
// <=128KB) preloaded once per block into LDS (XOR-swizzled). Each wave owns
// 16 A rows per tile, streamed global->VGPR with 2-tile ping-pong prefetch
// (named bufs, counted vmcnt(16), never 0). NO barriers after the initial
// sync -> waves free-run like a pure copy stream.

typedef unsigned short u16;
typedef u16 u16x8 __attribute__((ext_vector_type(8)));
typedef __bf16 bf16x8 __attribute__((ext_vector_type(8)));
typedef float f32x4 __attribute__((ext_vector_type(4)));

__device__ inline u16 f2bf(float f) {
  return __builtin_bit_cast(u16, (__bf16)f);
}

__device__ __forceinline__ void glds16(const void* g, void* l) {
  __builtin_amdgcn_global_load_lds(
      (const __attribute__((address_space(1))) void*)g,
      (__attribute__((address_space(3))) void*)l, 16, 0, 0);
}

// ---------------------------------------------------------------------------
// Weight prep: Wt[n][k] = bf16(W[k][n]). K=256 for all 4 matrices.
// grid (4,4,4): x->n-tile, y->k-tile, z->matrix.
__global__ __launch_bounds__(256) void wconv(
    const float* __restrict__ W0, const float* __restrict__ W1,
    const float* __restrict__ W2, const float* __restrict__ W3,
    u16* __restrict__ T0, u16* __restrict__ T1, u16* __restrict__ T2,
    u16* __restrict__ T3) {
  __shared__ u16 tile[64][65];
  const float* Ws[4] = {W0, W1, W2, W3};
  u16* Ts[4] = {T0, T1, T2, T3};
  const int Ns[4] = {256, 256, 128, 256};
  const int z = blockIdx.z;
  const int N = Ns[z];
  const int n0 = blockIdx.x * 64;
  if (n0 >= N) return;
  const int k0 = blockIdx.y * 64;
  const float* W = Ws[z];
  u16* Wt = Ts[z];
  const int tr = threadIdx.x >> 6;   // 0..3
  const int tc = threadIdx.x & 63;
#pragma unroll
  for (int r = 0; r < 64; r += 4)
    tile[r + tr][tc] = f2bf(W[(size_t)(k0 + r + tr) * N + n0 + tc]);
  __syncthreads();
#pragma unroll
  for (int r = 0; r < 64; r += 4)
    Wt[(size_t)(n0 + r + tr) * 256 + k0 + tc] = tile[tc][r + tr];
}

// ---------------------------------------------------------------------------
// C[M,N] = A[M,256]f32 (cast bf16) @ Wt[N,256]bf16^T + bias[N]
// WAVES waves, wave-tile = 16 rows x N. M-tile = WAVES*16.
// Bls[col][k] bf16: col*512 bytes + 16B chunks XOR-swizzled (phys = log ^
// (col&7)) -> frag ds_read_b128 spreads 8 lanes over all 32 banks (2-way ok).
// Persistent: block walks tiles t = bid, bid+G, ... ; B loaded once.
template <int WAVES, int NF, bool OUT_BF16>
__global__ __launch_bounds__(WAVES * 64, (WAVES == 16) ? 4 : 1)
void gemm_pers(const float* __restrict__ A, const u16* __restrict__ Wt,
               const float* __restrict__ bias, void* __restrict__ Cv,
               int M, int NT, int G) {
  __shared__ __align__(16) u16 Bls[NF * 16 * 256];  // NF*8 KB
  const int wave = threadIdx.x >> 6;
  const int lane = threadIdx.x & 63;
  const int lr = lane & 15;

  constexpr int MT = WAVES * 16;
  constexpr int NI = NF * 8 / WAVES;  // glds insts per wave (1KB each)

  // ---- B preload: each inst fills 2 swizzled cols (32 chunks each) ----
#pragma unroll
  for (int g = 0; g < NI; ++g) {
    int inst = wave * NI + g;
    int col = inst * 2 + (lane >> 5);
    int pc = lane & 31;            // physical 16B chunk within col
    int jc = pc ^ (col & 7);       // logical chunk stored at pc
    glds16((const char*)Wt + (size_t)col * 512 + (size_t)jc * 16,
           (char*)Bls + inst * 1024);
  }

  const int rit = wave * 16 + lr;   // A-frag row within tile
  const int kb = (lane >> 4) * 8;   // A-frag k-offset (elements)

  f32x4 bufE[16], bufO[16];

  auto loadT = [&](f32x4 (&buf)[16], int t) {
    long row = (long)t * MT + rit;
    if (row > (long)M - 1) row = M - 1;  // clamp (OOB tiles read row M-1)
    const float* ap = A + row * 256 + kb;
#pragma unroll
    for (int ks = 0; ks < 8; ++ks) {
      buf[ks * 2 + 0] = *(const f32x4*)(ap + ks * 32);
      buf[ks * 2 + 1] = *(const f32x4*)(ap + ks * 32 + 4);
    }
  };

  float bv[NF];
#pragma unroll
  for (int ni = 0; ni < NF; ++ni) bv[ni] = bias[ni * 16 + lr];

  auto compQ = [&](const f32x4 (&buf)[16], int t) {
    if (t >= NT) return;
    f32x4 acc[NF] = {};
#pragma unroll
    for (int ks = 0; ks < 8; ++ks) {
      bf16x8 af;
      af[0] = (__bf16)buf[ks * 2 + 0][0];
      af[1] = (__bf16)buf[ks * 2 + 0][1];
      af[2] = (__bf16)buf[ks * 2 + 0][2];
      af[3] = (__bf16)buf[ks * 2 + 0][3];
      af[4] = (__bf16)buf[ks * 2 + 1][0];
      af[5] = (__bf16)buf[ks * 2 + 1][1];
      af[6] = (__bf16)buf[ks * 2 + 1][2];
      af[7] = (__bf16)buf[ks * 2 + 1][3];
      const int jc = ks * 4 + (lane >> 4);  // logical chunk
      const int pc = jc ^ (lr & 7);         // physical chunk
#pragma unroll
      for (int ni = 0; ni < NF; ++ni) {
        int col = ni * 16 + lr;
        bf16x8 b = __builtin_bit_cast(
            bf16x8,
            *(const u16x8*)((const char*)Bls + col * 512 + pc * 16));
        acc[ni] = __builtin_amdgcn_mfma_f32_16x16x32_bf16(af, b, acc[ni],
                                                          0, 0, 0);
      }
    }
    // store: C row = t*MT + wave*16 + (lane>>4)*4 + r, col = ni*16 + lr
    const int rb = t * MT + wave * 16 + (lane >> 4) * 4;
#pragma unroll
    for (int ni = 0; ni < NF; ++ni) {
      int gcol = ni * 16 + lr;
#pragma unroll
      for (int r = 0; r < 4; ++r) {
        int grow = rb + r;
        if (grow < M) {
          float v = acc[ni][r] + bv[ni];
          if (OUT_BF16)
            ((u16*)Cv)[(size_t)grow * (NF * 16) + gcol] = f2bf(v);
          else
            ((float*)Cv)[(size_t)grow * (NF * 16) + gcol] = v;
        }
      }
    }
  };

  loadT(bufE, blockIdx.x);
  __syncthreads();  // B preload + bufE complete (one-time full drain)
  for (int t = blockIdx.x; t < NT; t += 2 * G) {
    loadT(bufO, t + G);
    asm volatile("s_waitcnt vmcnt(16)" ::: "memory");  // bufE ready
    compQ(bufE, t);
    loadT(bufE, t + 2 * G);
    asm volatile("s_waitcnt vmcnt(16)" ::: "memory");  // bufO ready
    compQ(bufO, t + G);
  }
}

// ---------------------------------------------------------------------------
// Fused qpost+sample: 8 queries/block. Phase 1: stage bbox + attn logits.
// Phase 2: pixel locs (sl) + softmax (sa). Phase 3: bilinear gather.
// 256 threads in gather = ql*32 + (h*4 + cg).
__global__ __launch_bounds__(256) void sample_fused(
    const float* __restrict__ Lgo, const float* __restrict__ Lga,
    const float* __restrict__ bbox, const u16* __restrict__ vbf,
    float* __restrict__ outs) {
  const int blk = blockIdx.x;
  const int i0 = blk * 8;
  const int t = threadIdx.x;
  __shared__ __align__(16) float sl[8 * 256];
  __shared__ __align__(16) float sa[8 * 128];
  __shared__ float sb[32];
  if (t < 32) sb[t] = bbox[(size_t)i0 * 4 + t];
#pragma unroll
  for (int j = 0; j < 4; ++j) {
    int idx = j * 256 + t;
    sa[idx] = Lga[(size_t)i0 * 128 + idx];
  }
  __syncthreads();
  // pixel-space locations from offset logits
#pragma unroll
  for (int j = 0; j < 8; ++j) {
    int idx = j * 256 + t;
    int ql = idx >> 8, e = idx & 255;
    float off = Lgo[(size_t)(i0 + ql) * 256 + e];
    int l = (e >> 3) & 3, xy = e & 1;
    float c = sb[ql * 4 + xy], wh = sb[ql * 4 + 2 + xy];
    sl[idx] = (c + off * 0.125f * wh) * (float)(80 >> l) - 0.5f;
  }
  // softmax over 16 per (query, head): threads 0..63
  if (t < 64) {
    int base = (t >> 3) * 128 + (t & 7) * 16;
    float mx = -3.0e38f;
#pragma unroll
    for (int j = 0; j < 16; ++j) mx = fmaxf(mx, sa[base + j]);
    float e[16];
    float s = 0.f;
#pragma unroll
    for (int j = 0; j < 16; ++j) {
      e[j] = __expf(sa[base + j] - mx);
      s += e[j];
    }
    float inv = 1.f / s;
#pragma unroll
    for (int j = 0; j < 16; ++j) sa[base + j] = e[j] * inv;
  }
  __syncthreads();

  const int ql = t >> 5;
  const int r = t & 31;
  const int h = r >> 2;
  const int cg = r & 3;
  const int choff = h * 32 + cg * 8;
  const int i = i0 + ql;
  const int b = blk / 125;
  const u16* vb = vbf + (size_t)b * 8500 * 256;

  float acc[8] = {};
  const int baseL[4] = {0, 6400, 8000, 8400};
  const int dimL[4] = {80, 40, 20, 10};

#pragma unroll
  for (int l = 0; l < 4; ++l) {
    const int W = dimL[l];
    const u16* vl = vb + (size_t)baseL[l] * 256 + choff;
#pragma unroll
    for (int p = 0; p < 4; ++p) {
      float x = sl[ql * 256 + h * 32 + l * 8 + p * 2 + 0];
      float y = sl[ql * 256 + h * 32 + l * 8 + p * 2 + 1];
      float aw = sa[ql * 128 + h * 16 + l * 4 + p];
      float x0f = floorf(x), y0f = floorf(y);
      float wx = x - x0f, wy = y - y0f;
      int x0 = (int)x0f, y0 = (int)y0f;
      int x1 = x0 + 1, y1 = y0 + 1;
      float fx0 = (x0 >= 0 && x0 < W) ? 1.f : 0.f;
      float fx1 = (x1 >= 0 && x1 < W) ? 1.f : 0.f;
      float fy0 = (y0 >= 0 && y0 < W) ? 1.f : 0.f;
      float fy1 = (y1 >= 0 && y1 < W) ? 1.f : 0.f;
      int xc0 = min(max(x0, 0), W - 1), xc1 = min(max(x1, 0), W - 1);
      int yc0 = min(max(y0, 0), W - 1), yc1 = min(max(y1, 0), W - 1);
      float w00 = aw * (1.f - wx) * (1.f - wy) * fx0 * fy0;
      float w01 = aw * wx * (1.f - wy) * fx1 * fy0;
      float w10 = aw * (1.f - wx) * wy * fx0 * fy1;
      float w11 = aw * wx * wy * fx1 * fy1;
      uint4 v00 = *(const uint4*)(vl + (size_t)(yc0 * W + xc0) * 256);
      uint4 v01 = *(const uint4*)(vl + (size_t)(yc0 * W + xc1) * 256);
      uint4 v10 = *(const uint4*)(vl + (size_t)(yc1 * W + xc0) * 256);
      uint4 v11 = *(const uint4*)(vl + (size_t)(yc1 * W + xc1) * 256);
      const uint32_t* p00 = (const uint32_t*)&v00;
      const uint32_t* p01 = (const uint32_t*)&v01;
      const uint32_t* p10 = (const uint32_t*)&v10;
      const uint32_t* p11 = (const uint32_t*)&v11;
#pragma unroll
      for (int k = 0; k < 4; ++k) {
        float a0 = __uint_as_float(p00[k] << 16);
        float a1 = __uint_as_float(p00[k] & 0xffff0000u);
        float b0 = __uint_as_float(p01[k] << 16);
        float b1 = __uint_as_float(p01[k] & 0xffff0000u);
        float c0 = __uint_as_float(p10[k] << 16);
        float c1 = __uint_as_float(p10[k] & 0xffff0000u);
        float d0 = __uint_as_float(p11[k] << 16);
        float d1 = __uint_as_float(p11[k] & 0xffff0000u);
        acc[2 * k] += w00 * a0 + w01 * b0 + w10 * c0 + w11 * d0;
        acc[2 * k + 1] += w00 * a1 + w01 * b1 + w10 * c1 + w11 * d1;
      }
    }
  }
  float4* op = (float4*)(outs + (size_t)i * 256 + choff);
  op[0] = make_float4(acc[0], acc[1], acc[2], acc[3]);
  op[1] = make_float4(acc[4], acc[5], acc[6], acc[7]);
}

extern "C" void kernel_launch(void* const* d_in, const int* in_sizes, int n_in,
                              void* d_out, int out_size, void* d_ws, size_t ws_size,
                              hipStream_t stream) {
  const float* query  = (const float*)d_in[0];
  const float* bbox   = (const float*)d_in[1];
  const float* value  = (const float*)d_in[2];
  const float* W_off  = (const float*)d_in[3];
  const float* b_off  = (const float*)d_in[4];
  const float* W_attn = (const float*)d_in[5];
  const float* b_attn = (const float*)d_in[6];
  const float* W_val  = (const float*)d_in[7];
  const float* b_val  = (const float*)d_in[8];
  const float* W_out  = (const float*)d_in[9];
  const float* b_out  = (const float*)d_in[10];
  float* out = (float*)d_out;

  // workspace layout
  char* w = (char*)d_ws;
  u16* vbf     = (u16*)w;                    // 69,632,000 B
  float* Lgo   = (float*)(w + 69632000);     // 16000*256*4 = 16,384,000 B
  float* Lga   = (float*)(w + 86016000);     // 16000*128*4 =  8,192,000 B
  float* outs  = (float*)(w + 94208000);     // 16000*256*4 = 16,384,000 B
  u16* Wt_val  = (u16*)(w + 110592000);      //    131,072 B
  u16* Wt_off  = (u16*)(w + 110723072);      //    131,072 B
  u16* Wt_attn = (u16*)(w + 110854144);      //     65,536 B
  u16* Wt_out  = (u16*)(w + 110919680);      //    131,072 B

  const int M_v = 16 * 8500;  // 136000
  const int M_q = 16 * 1000;  // 16000

  // 0) weight prep (bf16 transpose)
  wconv<<<dim3(4, 4, 4), 256, 0, stream>>>(W_val, W_off, W_attn, W_out,
                                           Wt_val, Wt_off, Wt_attn, Wt_out);
  // 1) value projection -> bf16 (persistent: 256 blocks x 16 waves)
  gemm_pers<16, 16, true><<<256, 1024, 0, stream>>>(
      value, Wt_val, b_val, (void*)vbf, M_v, 532, 256);
  // 2) offset logits [16000x256]
  gemm_pers<4, 16, false><<<250, 256, 0, stream>>>(
      query, Wt_off, b_off, (void*)Lgo, M_q, 250, 250);
  // 3) attn logits [16000x128]
  gemm_pers<4, 8, false><<<250, 256, 0, stream>>>(
      query, Wt_attn, b_attn, (void*)Lga, M_q, 250, 250);
  // 4) fused softmax/locs + bilinear sampling
  sample_fused<<<2000, 256, 0, stream>>>(Lgo, Lga, bbox, vbf, outs);
  // 5) output projection
  gemm_pers<4, 16, false><<<250, 256, 0, stream>>>(
      outs, Wt_out, b_out, (void*)out, M_q, 250, 250);
}

// Round 8
// 177.195 us; speedup vs baseline: 1.7613x; 1.7613x over previous
//
#include <hip/hip_runtime.h>
#include <cstdint>
#include <cstddef>

// DeformablePoseViT: bs=16, lq=1000, d=256, nh=8, L=4, P=4, dh=32
// value pyramid: (80,80),(40,40),(20,20),(10,10) -> lv=8500
//
// Pipeline:
//  0) wconv : Wt_* = bf16(W_*^T) [N][256] for the 4 weight matrices
//  1) gemm_pers<16,true> : vbf = bf16(value @ W_val + b_val) [136000x256]
//  2) gemm_pers<16,false>: Lgo = query @ W_off + b_off       [16000x256]
//  3) gemm_pers<8, false>: Lga = query @ W_attn + b_attn     [16000x128]
//  4) sample_fused : softmax+locs (in-block) + bilinear gather -> outs
//  5) gemm_pers<16,false>: d_out = outs @ W_out + b_out      [16000x256]
//
// gemm_pers v2: persistent, barrier-free after init. B resident in LDS
// (col-PERMUTED: storage slot s = ni*16+lr holds original col lr*NF+ni, so
// each lane's NF output cols are CONTIGUOUS -> coalesced dwordx4 C-stores).
// A staged per-wave-private via global_load_lds (2 x 4KB ping-pong, counted
// per-wave vmcnt — no cross-wave barriers, loads never drain to 0).

typedef unsigned short u16;
typedef u16 u16x8 __attribute__((ext_vector_type(8)));
typedef __bf16 bf16x8 __attribute__((ext_vector_type(8)));
typedef float f32x4 __attribute__((ext_vector_type(4)));

__device__ inline u16 f2bf(float f) {
  return __builtin_bit_cast(u16, (__bf16)f);
}

__device__ __forceinline__ void glds16(const void* g, void* l) {
  __builtin_amdgcn_global_load_lds(
      (const __attribute__((address_space(1))) void*)g,
      (__attribute__((address_space(3))) void*)l, 16, 0, 0);
}

// ---------------------------------------------------------------------------
// Weight prep: Wt[n][k] = bf16(W[k][n]). K=256 for all 4 matrices.
__global__ __launch_bounds__(256) void wconv(
    const float* __restrict__ W0, const float* __restrict__ W1,
    const float* __restrict__ W2, const float* __restrict__ W3,
    u16* __restrict__ T0, u16* __restrict__ T1, u16* __restrict__ T2,
    u16* __restrict__ T3) {
  __shared__ u16 tile[64][65];
  const float* Ws[4] = {W0, W1, W2, W3};
  u16* Ts[4] = {T0, T1, T2, T3};
  const int Ns[4] = {256, 256, 128, 256};
  const int z = blockIdx.z;
  const int N = Ns[z];
  const int n0 = blockIdx.x * 64;
  if (n0 >= N) return;
  const int k0 = blockIdx.y * 64;
  const float* W = Ws[z];
  u16* Wt = Ts[z];
  const int tr = threadIdx.x >> 6;   // 0..3
  const int tc = threadIdx.x & 63;
#pragma unroll
  for (int r = 0; r < 64; r += 4)
    tile[r + tr][tc] = f2bf(W[(size_t)(k0 + r + tr) * N + n0 + tc]);
  __syncthreads();
#pragma unroll
  for (int r = 0; r < 64; r += 4)
    Wt[(size_t)(n0 + r + tr) * 256 + k0 + tc] = tile[tc][r + tr];
}

// ---------------------------------------------------------------------------
// C[M,N] = A[M,256]f32 (cast bf16) @ Wt[N,256]bf16^T + bias[N]
// 256 threads = 4 waves, wave tile 32 rows x N (2 row-groups x NF frags).
// LDS: Bls N*512B (slot s = ni*16+lr <-> orig col lr*NF+ni; 16B chunks
// XOR-swizzled phys = logical ^ (s&7)); Asub 4 waves x 2 bufs x 4KB
// (32 rows x 32k f32, chunks XOR-swizzled by row&7).
// Per-tile chunk loop s=0..7: counted per-wave vmcnt (20/8/4), stage s+2.
template <int NF, bool OUT_BF16>
__global__ __launch_bounds__(256, 1) void gemm_pers(
    const float* __restrict__ A, const u16* __restrict__ Wt,
    const float* __restrict__ bias, void* __restrict__ Cv,
    int M, int NT, int G) {
  constexpr int N = NF * 16;
  __shared__ __align__(16) u16 Bls[N * 256];          // N*512 B (<=128KB)
  __shared__ __align__(16) float Asub[4 * 2 * 1024];  // 32 KB
  const int wave = threadIdx.x >> 6;
  const int lane = threadIdx.x & 63;
  const int lr = lane & 15;
  const int lj = lane >> 4;

  // ---- B preload (once per block) ----
#pragma unroll
  for (int g = 0; g < NF * 2; ++g) {
    int inst = wave * NF * 2 + g;
    int s = inst * 2 + (lane >> 5);
    int pc = lane & 31;
    int jc = pc ^ (s & 7);
    int c = (s & 15) * NF + (s >> 4);  // original column for slot s
    glds16((const char*)Wt + (size_t)c * 512 + (size_t)jc * 16,
           (char*)Bls + inst * 1024);
  }

  float bv[NF];
#pragma unroll
  for (int ni = 0; ni < NF; ++ni) bv[ni] = bias[lr * NF + ni];

  char* aw = (char*)Asub + wave * 8192;

  auto stageA = [&](int t, int s, int buf) {
#pragma unroll
    for (int i = 0; i < 4; ++i) {
      long row = (long)t * 128 + wave * 32 + i * 8 + (lane >> 3);
      if (row > (long)M - 1) row = M - 1;  // clamp (no predication on glds)
      int jc = (lane & 7) ^ (lane >> 3);
      glds16((const char*)A + row * 1024 + (size_t)s * 128 + (size_t)jc * 16,
             aw + buf * 4096 + i * 1024);
    }
  };

  stageA(blockIdx.x, 0, 0);
  stageA(blockIdx.x, 1, 1);
  __syncthreads();  // one-time: B + first A chunks resident

  for (int t = blockIdx.x; t < NT; t += G) {
    f32x4 acc[2][NF] = {};
#pragma unroll
    for (int s = 0; s < 8; ++s) {
      // counted per-wave waits; boundary includes C-stores in the FIFO
      if (s == 0 || s == 1)
        asm volatile("s_waitcnt vmcnt(20)" ::: "memory");
      else if (s == 2)
        asm volatile("s_waitcnt vmcnt(8)" ::: "memory");
      else
        asm volatile("s_waitcnt vmcnt(4)" ::: "memory");
      const char* ab = aw + (s & 1) * 4096;
      bf16x8 af[2];
#pragma unroll
      for (int rg = 0; rg < 2; ++rg) {
        int row = rg * 16 + lr;
        int sw = lane & 7;
        int j0 = lj * 2;
        f32x4 a0 = *(const f32x4*)(ab + row * 128 + ((j0 ^ sw) * 16));
        f32x4 a1 = *(const f32x4*)(ab + row * 128 + (((j0 + 1) ^ sw) * 16));
        bf16x8 v;
        v[0] = (__bf16)a0[0]; v[1] = (__bf16)a0[1];
        v[2] = (__bf16)a0[2]; v[3] = (__bf16)a0[3];
        v[4] = (__bf16)a1[0]; v[5] = (__bf16)a1[1];
        v[6] = (__bf16)a1[2]; v[7] = (__bf16)a1[3];
        af[rg] = v;
      }
#pragma unroll
      for (int ni = 0; ni < NF; ++ni) {
        int sl = ni * 16 + lr;
        int pc = (s * 4 + lj) ^ (sl & 7);
        bf16x8 b = __builtin_bit_cast(
            bf16x8, *(const u16x8*)((const char*)Bls + sl * 512 + pc * 16));
        acc[0][ni] = __builtin_amdgcn_mfma_f32_16x16x32_bf16(
            af[0], b, acc[0][ni], 0, 0, 0);
        acc[1][ni] = __builtin_amdgcn_mfma_f32_16x16x32_bf16(
            af[1], b, acc[1][ni], 0, 0, 0);
      }
      if (s < 6)
        stageA(t, s + 2, s & 1);
      else
        stageA(t + G, s - 6, s & 1);  // next tile's chunks 0,1
    }
    // epilogue: lane writes original cols lr*NF .. lr*NF+NF-1 (contiguous)
#pragma unroll
    for (int rg = 0; rg < 2; ++rg) {
#pragma unroll
      for (int r = 0; r < 4; ++r) {
        long grow = (long)t * 128 + wave * 32 + rg * 16 + lj * 4 + r;
        if (grow >= M) continue;
        if (OUT_BF16) {
          bf16x8 lo, hi;
#pragma unroll
          for (int j = 0; j < 8; ++j) {
            lo[j] = (__bf16)(acc[rg][j][r] + bv[j]);
            hi[j] = (__bf16)(acc[rg][8 + j][r] + bv[8 + j]);
          }
          u16* pC = (u16*)Cv + grow * N + lr * NF;
          *(u16x8*)pC = __builtin_bit_cast(u16x8, lo);
          *(u16x8*)(pC + 8) = __builtin_bit_cast(u16x8, hi);
        } else {
#pragma unroll
          for (int q = 0; q < NF / 4; ++q) {
            f32x4 v;
#pragma unroll
            for (int j = 0; j < 4; ++j)
              v[j] = acc[rg][q * 4 + j][r] + bv[q * 4 + j];
            *(f32x4*)((float*)Cv + grow * N + lr * NF + q * 4) = v;
          }
        }
      }
    }
  }
}

// ---------------------------------------------------------------------------
// Fused qpost+sample: 8 queries/block, 256 threads = ql*32 + (h*4 + cg)
__global__ __launch_bounds__(256) void sample_fused(
    const float* __restrict__ Lgo, const float* __restrict__ Lga,
    const float* __restrict__ bbox, const u16* __restrict__ vbf,
    float* __restrict__ outs) {
  const int blk = blockIdx.x;
  const int i0 = blk * 8;
  const int t = threadIdx.x;
  __shared__ __align__(16) float sl[8 * 256];
  __shared__ __align__(16) float sa[8 * 128];
  __shared__ float sb[32];
  if (t < 32) sb[t] = bbox[(size_t)i0 * 4 + t];
#pragma unroll
  for (int j = 0; j < 4; ++j) {
    int idx = j * 256 + t;
    sa[idx] = Lga[(size_t)i0 * 128 + idx];
  }
  __syncthreads();
#pragma unroll
  for (int j = 0; j < 8; ++j) {
    int idx = j * 256 + t;
    int ql = idx >> 8, e = idx & 255;
    float off = Lgo[(size_t)(i0 + ql) * 256 + e];
    int l = (e >> 3) & 3, xy = e & 1;
    float c = sb[ql * 4 + xy], wh = sb[ql * 4 + 2 + xy];
    sl[idx] = (c + off * 0.125f * wh) * (float)(80 >> l) - 0.5f;
  }
  if (t < 64) {
    int base = (t >> 3) * 128 + (t & 7) * 16;
    float mx = -3.0e38f;
#pragma unroll
    for (int j = 0; j < 16; ++j) mx = fmaxf(mx, sa[base + j]);
    float e[16];
    float s = 0.f;
#pragma unroll
    for (int j = 0; j < 16; ++j) {
      e[j] = __expf(sa[base + j] - mx);
      s += e[j];
    }
    float inv = 1.f / s;
#pragma unroll
    for (int j = 0; j < 16; ++j) sa[base + j] = e[j] * inv;
  }
  __syncthreads();

  const int ql = t >> 5;
  const int r = t & 31;
  const int h = r >> 2;
  const int cg = r & 3;
  const int choff = h * 32 + cg * 8;
  const int i = i0 + ql;
  const int b = blk / 125;
  const u16* vb = vbf + (size_t)b * 8500 * 256;

  float acc[8] = {};
  const int baseL[4] = {0, 6400, 8000, 8400};
  const int dimL[4] = {80, 40, 20, 10};

#pragma unroll
  for (int l = 0; l < 4; ++l) {
    const int W = dimL[l];
    const u16* vl = vb + (size_t)baseL[l] * 256 + choff;
#pragma unroll
    for (int p = 0; p < 4; ++p) {
      float x = sl[ql * 256 + h * 32 + l * 8 + p * 2 + 0];
      float y = sl[ql * 256 + h * 32 + l * 8 + p * 2 + 1];
      float aw = sa[ql * 128 + h * 16 + l * 4 + p];
      float x0f = floorf(x), y0f = floorf(y);
      float wx = x - x0f, wy = y - y0f;
      int x0 = (int)x0f, y0 = (int)y0f;
      int x1 = x0 + 1, y1 = y0 + 1;
      float fx0 = (x0 >= 0 && x0 < W) ? 1.f : 0.f;
      float fx1 = (x1 >= 0 && x1 < W) ? 1.f : 0.f;
      float fy0 = (y0 >= 0 && y0 < W) ? 1.f : 0.f;
      float fy1 = (y1 >= 0 && y1 < W) ? 1.f : 0.f;
      int xc0 = min(max(x0, 0), W - 1), xc1 = min(max(x1, 0), W - 1);
      int yc0 = min(max(y0, 0), W - 1), yc1 = min(max(y1, 0), W - 1);
      float w00 = aw * (1.f - wx) * (1.f - wy) * fx0 * fy0;
      float w01 = aw * wx * (1.f - wy) * fx1 * fy0;
      float w10 = aw * (1.f - wx) * wy * fx0 * fy1;
      float w11 = aw * wx * wy * fx1 * fy1;
      uint4 v00 = *(const uint4*)(vl + (size_t)(yc0 * W + xc0) * 256);
      uint4 v01 = *(const uint4*)(vl + (size_t)(yc0 * W + xc1) * 256);
      uint4 v10 = *(const uint4*)(vl + (size_t)(yc1 * W + xc0) * 256);
      uint4 v11 = *(const uint4*)(vl + (size_t)(yc1 * W + xc1) * 256);
      const uint32_t* p00 = (const uint32_t*)&v00;
      const uint32_t* p01 = (const uint32_t*)&v01;
      const uint32_t* p10 = (const uint32_t*)&v10;
      const uint32_t* p11 = (const uint32_t*)&v11;
#pragma unroll
      for (int k = 0; k < 4; ++k) {
        float a0 = __uint_as_float(p00[k] << 16);
        float a1 = __uint_as_float(p00[k] & 0xffff0000u);
        float b0 = __uint_as_float(p01[k] << 16);
        float b1 = __uint_as_float(p01[k] & 0xffff0000u);
        float c0 = __uint_as_float(p10[k] << 16);
        float c1 = __uint_as_float(p10[k] & 0xffff0000u);
        float d0 = __uint_as_float(p11[k] << 16);
        float d1 = __uint_as_float(p11[k] & 0xffff0000u);
        acc[2 * k] += w00 * a0 + w01 * b0 + w10 * c0 + w11 * d0;
        acc[2 * k + 1] += w00 * a1 + w01 * b1 + w10 * c1 + w11 * d1;
      }
    }
  }
  float4* op = (float4*)(outs + (size_t)i * 256 + choff);
  op[0] = make_float4(acc[0], acc[1], acc[2], acc[3]);
  op[1] = make_float4(acc[4], acc[5], acc[6], acc[7]);
}

extern "C" void kernel_launch(void* const* d_in, const int* in_sizes, int n_in,
                              void* d_out, int out_size, void* d_ws, size_t ws_size,
                              hipStream_t stream) {
  const float* query  = (const float*)d_in[0];
  const float* bbox   = (const float*)d_in[1];
  const float* value  = (const float*)d_in[2];
  const float* W_off  = (const float*)d_in[3];
  const float* b_off  = (const float*)d_in[4];
  const float* W_attn = (const float*)d_in[5];
  const float* b_attn = (const float*)d_in[6];
  const float* W_val  = (const float*)d_in[7];
  const float* b_val  = (const float*)d_in[8];
  const float* W_out  = (const float*)d_in[9];
  const float* b_out  = (const float*)d_in[10];
  float* out = (float*)d_out;

  // workspace layout
  char* w = (char*)d_ws;
  u16* vbf     = (u16*)w;                    // 69,632,000 B
  float* Lgo   = (float*)(w + 69632000);     // 16,384,000 B
  float* Lga   = (float*)(w + 86016000);     //  8,192,000 B
  float* outs  = (float*)(w + 94208000);     // 16,384,000 B
  u16* Wt_val  = (u16*)(w + 110592000);      //    131,072 B
  u16* Wt_off  = (u16*)(w + 110723072);      //    131,072 B
  u16* Wt_attn = (u16*)(w + 110854144);      //     65,536 B
  u16* Wt_out  = (u16*)(w + 110919680);      //    131,072 B

  const int M_v = 16 * 8500;  // 136000
  const int M_q = 16 * 1000;  // 16000

  // 0) weight prep (bf16 transpose)
  wconv<<<dim3(4, 4, 4), 256, 0, stream>>>(W_val, W_off, W_attn, W_out,
                                           Wt_val, Wt_off, Wt_attn, Wt_out);
  // 1) value projection -> bf16 (persistent, 1 block/CU)
  gemm_pers<16, true><<<256, 256, 0, stream>>>(
      value, Wt_val, b_val, (void*)vbf, M_v, 1063, 256);
  // 2) offset logits [16000x256]
  gemm_pers<16, false><<<125, 256, 0, stream>>>(
      query, Wt_off, b_off, (void*)Lgo, M_q, 125, 125);
  // 3) attn logits [16000x128]
  gemm_pers<8, false><<<125, 256, 0, stream>>>(
      query, Wt_attn, b_attn, (void*)Lga, M_q, 125, 125);
  // 4) fused softmax/locs + bilinear sampling
  sample_fused<<<2000, 256, 0, stream>>>(Lgo, Lga, bbox, vbf, outs);
  // 5) output projection
  gemm_pers<16, false><<<125, 256, 0, stream>>>(
      outs, Wt_out, b_out, (void*)out, M_q, 125, 125);
}

// Round 9
// 133.303 us; speedup vs baseline: 2.3413x; 1.3293x over previous
//
#include <hip/hip_runtime.h>
#include <cstdint>
#include <cstddef>

// DeformablePoseViT: bs=16, lq=1000, d=256, nh=8, L=4, P=4, dh=32
// value pyramid: (80,80),(40,40),(20,20),(10,10) -> lv=8500
//
// Pipeline:
//  0) wconv : Wt_* = bf16(W_*^T) [N][256] for the 4 weight matrices
//  1) gemm_pers<16,true> : vbf = bf16(value @ W_val + b_val) [136000x256]
//  2) gemm_pers<16,false>: Lgo = query @ W_off + b_off       [16000x256]
//  3) gemm_pers<8, false>: Lga = query @ W_attn + b_attn     [16000x128]
//  4) sample_fused : softmax + weight/offset precompute (LDS) + gather
//  5) gemm_pers<16,false>: d_out = outs @ W_out + b_out      [16000x256]

typedef unsigned short u16;
typedef u16 u16x8 __attribute__((ext_vector_type(8)));
typedef __bf16 bf16x8 __attribute__((ext_vector_type(8)));
typedef float f32x4 __attribute__((ext_vector_type(4)));

__device__ inline u16 f2bf(float f) {
  return __builtin_bit_cast(u16, (__bf16)f);
}

__device__ __forceinline__ void glds16(const void* g, void* l) {
  __builtin_amdgcn_global_load_lds(
      (const __attribute__((address_space(1))) void*)g,
      (__attribute__((address_space(3))) void*)l, 16, 0, 0);
}

// ---------------------------------------------------------------------------
// Weight prep: Wt[n][k] = bf16(W[k][n]). K=256 for all 4 matrices.
__global__ __launch_bounds__(256) void wconv(
    const float* __restrict__ W0, const float* __restrict__ W1,
    const float* __restrict__ W2, const float* __restrict__ W3,
    u16* __restrict__ T0, u16* __restrict__ T1, u16* __restrict__ T2,
    u16* __restrict__ T3) {
  __shared__ u16 tile[64][65];
  const float* Ws[4] = {W0, W1, W2, W3};
  u16* Ts[4] = {T0, T1, T2, T3};
  const int Ns[4] = {256, 256, 128, 256};
  const int z = blockIdx.z;
  const int N = Ns[z];
  const int n0 = blockIdx.x * 64;
  if (n0 >= N) return;
  const int k0 = blockIdx.y * 64;
  const float* W = Ws[z];
  u16* Wt = Ts[z];
  const int tr = threadIdx.x >> 6;   // 0..3
  const int tc = threadIdx.x & 63;
#pragma unroll
  for (int r = 0; r < 64; r += 4)
    tile[r + tr][tc] = f2bf(W[(size_t)(k0 + r + tr) * N + n0 + tc]);
  __syncthreads();
#pragma unroll
  for (int r = 0; r < 64; r += 4)
    Wt[(size_t)(n0 + r + tr) * 256 + k0 + tc] = tile[tc][r + tr];
}

// ---------------------------------------------------------------------------
// C[M,N] = A[M,256]f32 (cast bf16) @ Wt[N,256]bf16^T + bias[N]
// Persistent, barrier-free after init (see R7 notes). Unchanged this round.
template <int NF, bool OUT_BF16>
__global__ __launch_bounds__(256, 1) void gemm_pers(
    const float* __restrict__ A, const u16* __restrict__ Wt,
    const float* __restrict__ bias, void* __restrict__ Cv,
    int M, int NT, int G) {
  constexpr int N = NF * 16;
  __shared__ __align__(16) u16 Bls[N * 256];          // N*512 B (<=128KB)
  __shared__ __align__(16) float Asub[4 * 2 * 1024];  // 32 KB
  const int wave = threadIdx.x >> 6;
  const int lane = threadIdx.x & 63;
  const int lr = lane & 15;
  const int lj = lane >> 4;

  // ---- B preload (once per block) ----
#pragma unroll
  for (int g = 0; g < NF * 2; ++g) {
    int inst = wave * NF * 2 + g;
    int s = inst * 2 + (lane >> 5);
    int pc = lane & 31;
    int jc = pc ^ (s & 7);
    int c = (s & 15) * NF + (s >> 4);  // original column for slot s
    glds16((const char*)Wt + (size_t)c * 512 + (size_t)jc * 16,
           (char*)Bls + inst * 1024);
  }

  float bv[NF];
#pragma unroll
  for (int ni = 0; ni < NF; ++ni) bv[ni] = bias[lr * NF + ni];

  char* aw = (char*)Asub + wave * 8192;

  auto stageA = [&](int t, int s, int buf) {
#pragma unroll
    for (int i = 0; i < 4; ++i) {
      long row = (long)t * 128 + wave * 32 + i * 8 + (lane >> 3);
      if (row > (long)M - 1) row = M - 1;  // clamp (no predication on glds)
      int jc = (lane & 7) ^ (lane >> 3);
      glds16((const char*)A + row * 1024 + (size_t)s * 128 + (size_t)jc * 16,
             aw + buf * 4096 + i * 1024);
    }
  };

  stageA(blockIdx.x, 0, 0);
  stageA(blockIdx.x, 1, 1);
  __syncthreads();  // one-time: B + first A chunks resident

  for (int t = blockIdx.x; t < NT; t += G) {
    f32x4 acc[2][NF] = {};
#pragma unroll
    for (int s = 0; s < 8; ++s) {
      if (s == 0 || s == 1)
        asm volatile("s_waitcnt vmcnt(20)" ::: "memory");
      else if (s == 2)
        asm volatile("s_waitcnt vmcnt(8)" ::: "memory");
      else
        asm volatile("s_waitcnt vmcnt(4)" ::: "memory");
      const char* ab = aw + (s & 1) * 4096;
      bf16x8 af[2];
#pragma unroll
      for (int rg = 0; rg < 2; ++rg) {
        int row = rg * 16 + lr;
        int sw = lane & 7;
        int j0 = lj * 2;
        f32x4 a0 = *(const f32x4*)(ab + row * 128 + ((j0 ^ sw) * 16));
        f32x4 a1 = *(const f32x4*)(ab + row * 128 + (((j0 + 1) ^ sw) * 16));
        bf16x8 v;
        v[0] = (__bf16)a0[0]; v[1] = (__bf16)a0[1];
        v[2] = (__bf16)a0[2]; v[3] = (__bf16)a0[3];
        v[4] = (__bf16)a1[0]; v[5] = (__bf16)a1[1];
        v[6] = (__bf16)a1[2]; v[7] = (__bf16)a1[3];
        af[rg] = v;
      }
#pragma unroll
      for (int ni = 0; ni < NF; ++ni) {
        int sl = ni * 16 + lr;
        int pc = (s * 4 + lj) ^ (sl & 7);
        bf16x8 b = __builtin_bit_cast(
            bf16x8, *(const u16x8*)((const char*)Bls + sl * 512 + pc * 16));
        acc[0][ni] = __builtin_amdgcn_mfma_f32_16x16x32_bf16(
            af[0], b, acc[0][ni], 0, 0, 0);
        acc[1][ni] = __builtin_amdgcn_mfma_f32_16x16x32_bf16(
            af[1], b, acc[1][ni], 0, 0, 0);
      }
      if (s < 6)
        stageA(t, s + 2, s & 1);
      else
        stageA(t + G, s - 6, s & 1);  // next tile's chunks 0,1
    }
    // epilogue: lane writes original cols lr*NF .. lr*NF+NF-1 (contiguous)
#pragma unroll
    for (int rg = 0; rg < 2; ++rg) {
#pragma unroll
      for (int r = 0; r < 4; ++r) {
        long grow = (long)t * 128 + wave * 32 + rg * 16 + lj * 4 + r;
        if (grow >= M) continue;
        if (OUT_BF16) {
          bf16x8 lo, hi;
#pragma unroll
          for (int j = 0; j < 8; ++j) {
            lo[j] = (__bf16)(acc[rg][j][r] + bv[j]);
            hi[j] = (__bf16)(acc[rg][8 + j][r] + bv[8 + j]);
          }
          u16* pC = (u16*)Cv + grow * N + lr * NF;
          *(u16x8*)pC = __builtin_bit_cast(u16x8, lo);
          *(u16x8*)(pC + 8) = __builtin_bit_cast(u16x8, hi);
        } else {
#pragma unroll
          for (int q = 0; q < NF / 4; ++q) {
            f32x4 v;
#pragma unroll
            for (int j = 0; j < 4; ++j)
              v[j] = acc[rg][q * 4 + j][r] + bv[q * 4 + j];
            *(f32x4*)((float*)Cv + grow * N + lr * NF + q * 4) = v;
          }
        }
      }
    }
  }
}

// ---------------------------------------------------------------------------
// sample_fused v3: XCD batch-affinity remap + LDS weight/offset precompute.
// Block = 8 queries. Phase 0: softmax (64 threads). Phase A: 1024 (ql,h,l,p)
// items -> int4 corner byte-offsets + float4 attn-folded weights in LDS
// (slot swizzle pt^h -> conflict-free phase-B reads). Phase B: gather+FMA.
__global__ __launch_bounds__(256, 4) void sample_fused(
    const float* __restrict__ Lgo, const float* __restrict__ Lga,
    const float* __restrict__ bbox, const u16* __restrict__ vbf,
    float* __restrict__ outs) {
  const int t = threadIdx.x;
  // XCD affinity: blocks i = xcd (mod 8) share one batch at a time
  const int bi = blockIdx.x;
  const int xcd = bi & 7;
  const int j = bi >> 3;            // 0..249
  const int half = (j >= 125) ? 1 : 0;
  const int batch = xcd + 8 * half;
  const int qb = j - 125 * half;    // 0..124
  const int i0 = (batch * 125 + qb) * 8;  // first global query index

  __shared__ __align__(16) float sa[8 * 128];
  __shared__ __align__(16) int4 soff[1024];
  __shared__ __align__(16) float4 sw4[1024];
  __shared__ float sb[32];
  if (t < 32) sb[t] = bbox[(size_t)i0 * 4 + t];
  ((float4*)sa)[t] = ((const float4*)(Lga + (size_t)i0 * 128))[t];
  __syncthreads();
  // softmax over 16 per (query, head): threads 0..63
  if (t < 64) {
    int base = (t >> 3) * 128 + (t & 7) * 16;
    float mx = -3.0e38f;
#pragma unroll
    for (int k = 0; k < 16; ++k) mx = fmaxf(mx, sa[base + k]);
    float e[16];
    float s = 0.f;
#pragma unroll
    for (int k = 0; k < 16; ++k) {
      e[k] = __expf(sa[base + k] - mx);
      s += e[k];
    }
    float inv = 1.f / s;
#pragma unroll
    for (int k = 0; k < 16; ++k) sa[base + k] = e[k] * inv;
  }
  __syncthreads();
  // phase A: per-item corner offsets + folded weights
#pragma unroll
  for (int it = 0; it < 4; ++it) {
    int idx = it * 256 + t;
    int ql = idx >> 7;
    int rest = idx & 127;
    int h = rest >> 4;
    int pt = rest & 15;
    int l = pt >> 2;
    int W = 80 >> l;
    float offx = Lgo[(size_t)(i0 + ql) * 256 + h * 32 + pt * 2];
    float offy = Lgo[(size_t)(i0 + ql) * 256 + h * 32 + pt * 2 + 1];
    float xf = (sb[ql * 4 + 0] + offx * 0.125f * sb[ql * 4 + 2]) * (float)W - 0.5f;
    float yf = (sb[ql * 4 + 1] + offy * 0.125f * sb[ql * 4 + 3]) * (float)W - 0.5f;
    float aw = sa[ql * 128 + h * 16 + pt];
    float x0f = floorf(xf), y0f = floorf(yf);
    float wx = xf - x0f, wy = yf - y0f;
    int x0 = (int)x0f, y0 = (int)y0f;
    int x1 = x0 + 1, y1 = y0 + 1;
    float fx0 = (x0 >= 0 && x0 < W) ? 1.f : 0.f;
    float fx1 = (x1 >= 0 && x1 < W) ? 1.f : 0.f;
    float fy0 = (y0 >= 0 && y0 < W) ? 1.f : 0.f;
    float fy1 = (y1 >= 0 && y1 < W) ? 1.f : 0.f;
    int xc0 = min(max(x0, 0), W - 1), xc1 = min(max(x1, 0), W - 1);
    int yc0 = min(max(y0, 0), W - 1), yc1 = min(max(y1, 0), W - 1);
    // level base (elements): (25600 - (25600>>2l))/3 = 0,6400,8000,8400
    int baseb = ((25600 - (25600 >> (2 * l))) / 3) * 512;  // bytes (512B/px)
    int4 o;
    o.x = baseb + (yc0 * W + xc0) * 512;
    o.y = baseb + (yc0 * W + xc1) * 512;
    o.z = baseb + (yc1 * W + xc0) * 512;
    o.w = baseb + (yc1 * W + xc1) * 512;
    float aw0 = aw * (1.f - wy), aw1 = aw * wy;
    float4 wv;
    wv.x = aw0 * (1.f - wx) * fx0 * fy0;
    wv.y = aw0 * wx * fx1 * fy0;
    wv.z = aw1 * (1.f - wx) * fx0 * fy1;
    wv.w = aw1 * wx * fx1 * fy1;
    int phys = ql * 128 + h * 16 + (pt ^ h);
    soff[phys] = o;
    sw4[phys] = wv;
  }
  __syncthreads();
  // phase B: gather + weighted accumulate
  const int ql = t >> 5;
  const int r = t & 31;
  const int h = r >> 2;
  const int cg = r & 3;
  const int chb = (h * 32 + cg * 8) * 2;  // byte offset of 8-ch group
  const char* vbb = (const char*)vbf + (size_t)batch * 8500 * 512 + chb;
  float acc[8] = {};
#pragma unroll 2
  for (int pt = 0; pt < 16; ++pt) {
    int phys = ql * 128 + h * 16 + (pt ^ h);
    int4 o = soff[phys];
    float4 wv = sw4[phys];
    uint4 v00 = *(const uint4*)(vbb + o.x);
    uint4 v01 = *(const uint4*)(vbb + o.y);
    uint4 v10 = *(const uint4*)(vbb + o.z);
    uint4 v11 = *(const uint4*)(vbb + o.w);
    const uint32_t* p00 = (const uint32_t*)&v00;
    const uint32_t* p01 = (const uint32_t*)&v01;
    const uint32_t* p10 = (const uint32_t*)&v10;
    const uint32_t* p11 = (const uint32_t*)&v11;
#pragma unroll
    for (int k = 0; k < 4; ++k) {
      float a0 = __uint_as_float(p00[k] << 16);
      float a1 = __uint_as_float(p00[k] & 0xffff0000u);
      float b0 = __uint_as_float(p01[k] << 16);
      float b1 = __uint_as_float(p01[k] & 0xffff0000u);
      float c0 = __uint_as_float(p10[k] << 16);
      float c1 = __uint_as_float(p10[k] & 0xffff0000u);
      float d0 = __uint_as_float(p11[k] << 16);
      float d1 = __uint_as_float(p11[k] & 0xffff0000u);
      acc[2 * k] += wv.x * a0 + wv.y * b0 + wv.z * c0 + wv.w * d0;
      acc[2 * k + 1] += wv.x * a1 + wv.y * b1 + wv.z * c1 + wv.w * d1;
    }
  }
  float4* op = (float4*)(outs + (size_t)(i0 + ql) * 256 + h * 32 + cg * 8);
  op[0] = make_float4(acc[0], acc[1], acc[2], acc[3]);
  op[1] = make_float4(acc[4], acc[5], acc[6], acc[7]);
}

extern "C" void kernel_launch(void* const* d_in, const int* in_sizes, int n_in,
                              void* d_out, int out_size, void* d_ws, size_t ws_size,
                              hipStream_t stream) {
  const float* query  = (const float*)d_in[0];
  const float* bbox   = (const float*)d_in[1];
  const float* value  = (const float*)d_in[2];
  const float* W_off  = (const float*)d_in[3];
  const float* b_off  = (const float*)d_in[4];
  const float* W_attn = (const float*)d_in[5];
  const float* b_attn = (const float*)d_in[6];
  const float* W_val  = (const float*)d_in[7];
  const float* b_val  = (const float*)d_in[8];
  const float* W_out  = (const float*)d_in[9];
  const float* b_out  = (const float*)d_in[10];
  float* out = (float*)d_out;

  // workspace layout
  char* w = (char*)d_ws;
  u16* vbf     = (u16*)w;                    // 69,632,000 B
  float* Lgo   = (float*)(w + 69632000);     // 16,384,000 B
  float* Lga   = (float*)(w + 86016000);     //  8,192,000 B
  float* outs  = (float*)(w + 94208000);     // 16,384,000 B
  u16* Wt_val  = (u16*)(w + 110592000);      //    131,072 B
  u16* Wt_off  = (u16*)(w + 110723072);      //    131,072 B
  u16* Wt_attn = (u16*)(w + 110854144);      //     65,536 B
  u16* Wt_out  = (u16*)(w + 110919680);      //    131,072 B

  const int M_v = 16 * 8500;  // 136000
  const int M_q = 16 * 1000;  // 16000

  // 0) weight prep (bf16 transpose)
  wconv<<<dim3(4, 4, 4), 256, 0, stream>>>(W_val, W_off, W_attn, W_out,
                                           Wt_val, Wt_off, Wt_attn, Wt_out);
  // 1) value projection -> bf16 (persistent, 1 block/CU)
  gemm_pers<16, true><<<256, 256, 0, stream>>>(
      value, Wt_val, b_val, (void*)vbf, M_v, 1063, 256);
  // 2) offset logits [16000x256]
  gemm_pers<16, false><<<125, 256, 0, stream>>>(
      query, Wt_off, b_off, (void*)Lgo, M_q, 125, 125);
  // 3) attn logits [16000x128]
  gemm_pers<8, false><<<125, 256, 0, stream>>>(
      query, Wt_attn, b_attn, (void*)Lga, M_q, 125, 125);
  // 4) fused softmax/locs + bilinear sampling (XCD batch affinity)
  sample_fused<<<2000, 256, 0, stream>>>(Lgo, Lga, bbox, vbf, outs);
  // 5) output projection
  gemm_pers<16, false><<<125, 256, 0, stream>>>(
      outs, Wt_out, b_out, (void*)out, M_q, 125, 125);
}

// Round 10
// 124.717 us; speedup vs baseline: 2.5025x; 1.0688x over previous
//
#include <hip/hip_runtime.h>
#include <cstdint>
#include <cstddef>

// DeformablePoseViT: bs=16, lq=1000, d=256, nh=8, L=4, P=4, dh=32
// value pyramid: (80,80),(40,40),(20,20),(10,10) -> lv=8500
//
// Pipeline:
//  0) wconv : Wt_* = bf16(W_*^T) [N][256] for the 4 weight matrices
//  1) gemm_p2<8,16,true> : vbf = bf16(value @ W_val + b_val) [136000x256]
//  2) gemm_p2<4,16,false>: Lgo = query @ W_off + b_off       [16000x256]
//  3) gemm_p2<4,8,false> : Lga = query @ W_attn + b_attn     [16000x128]
//  4) sample_fused : softmax + weight/offset precompute (LDS) + gather
//  5) gemm_p2<4,16,false>: d_out = outs @ W_out + b_out      [16000x256]
//
// gemm_p2: persistent B-resident GEMM, WAVES waves x 16 rows/wave.
// B (N x 256 bf16) resident in LDS, col-permuted (slot ni*16+lr <-> orig col
// lr*NF+ni -> contiguous per-lane C stores) + 16B-chunk XOR swizzle.
// A staged per-wave-private via global_load_lds 2x2KB ping-pong, counted
// in-order vmcnt schedule (next-tile chunks staged BEFORE epilogue stores so
// s<2 waits need not drain stores). No cross-wave barriers after init.

typedef unsigned short u16;
typedef u16 u16x8 __attribute__((ext_vector_type(8)));
typedef __bf16 bf16x8 __attribute__((ext_vector_type(8)));
typedef float f32x4 __attribute__((ext_vector_type(4)));

__device__ inline u16 f2bf(float f) {
  return __builtin_bit_cast(u16, (__bf16)f);
}

__device__ __forceinline__ void glds16(const void* g, void* l) {
  __builtin_amdgcn_global_load_lds(
      (const __attribute__((address_space(1))) void*)g,
      (__attribute__((address_space(3))) void*)l, 16, 0, 0);
}

// ---------------------------------------------------------------------------
// Weight prep: Wt[n][k] = bf16(W[k][n]). K=256 for all 4 matrices.
__global__ __launch_bounds__(256) void wconv(
    const float* __restrict__ W0, const float* __restrict__ W1,
    const float* __restrict__ W2, const float* __restrict__ W3,
    u16* __restrict__ T0, u16* __restrict__ T1, u16* __restrict__ T2,
    u16* __restrict__ T3) {
  __shared__ u16 tile[64][65];
  const float* Ws[4] = {W0, W1, W2, W3};
  u16* Ts[4] = {T0, T1, T2, T3};
  const int Ns[4] = {256, 256, 128, 256};
  const int z = blockIdx.z;
  const int N = Ns[z];
  const int n0 = blockIdx.x * 64;
  if (n0 >= N) return;
  const int k0 = blockIdx.y * 64;
  const float* W = Ws[z];
  u16* Wt = Ts[z];
  const int tr = threadIdx.x >> 6;   // 0..3
  const int tc = threadIdx.x & 63;
#pragma unroll
  for (int r = 0; r < 64; r += 4)
    tile[r + tr][tc] = f2bf(W[(size_t)(k0 + r + tr) * N + n0 + tc]);
  __syncthreads();
#pragma unroll
  for (int r = 0; r < 64; r += 4)
    Wt[(size_t)(n0 + r + tr) * 256 + k0 + tc] = tile[tc][r + tr];
}

// ---------------------------------------------------------------------------
// C[M,N] = A[M,256]f32 (cast bf16) @ Wt[N,256]bf16^T + bias[N]
template <int WAVES, int NF, bool OUT_BF16>
__global__ __launch_bounds__(WAVES * 64, 1) void gemm_p2(
    const float* __restrict__ A, const u16* __restrict__ Wt,
    const float* __restrict__ bias, void* __restrict__ Cv,
    int M, int NT, int G) {
  constexpr int N = NF * 16;
  constexpr int TR = WAVES * 16;                  // tile rows
  constexpr int STN = OUT_BF16 ? (NF / 2) : NF;   // stores/lane/tile
  __shared__ __align__(16) u16 Bls[N * 256];      // N*512 B
  __shared__ __align__(16) float Asub[WAVES * 1024];  // WAVES*4 KB
  const int wave = threadIdx.x >> 6;
  const int lane = threadIdx.x & 63;
  const int lr = lane & 15;
  const int lj = lane >> 4;

  // ---- B preload (once per block): NF*8 insts of 1KB (2 permuted cols) ----
  constexpr int NI = NF * 8 / WAVES;
#pragma unroll
  for (int g = 0; g < NI; ++g) {
    int inst = wave * NI + g;
    int s2 = inst * 2 + (lane >> 5);
    int pc = lane & 31;
    int jc = pc ^ (s2 & 7);
    int c = (s2 & 15) * NF + (s2 >> 4);  // original column for slot s2
    glds16((const char*)Wt + (size_t)c * 512 + (size_t)jc * 16,
           (char*)Bls + inst * 1024);
  }

  float bv[NF];
#pragma unroll
  for (int ni = 0; ni < NF; ++ni) bv[ni] = bias[lr * NF + ni];

  char* aw = (char*)Asub + wave * 4096;

  auto stageA = [&](int t, int s, int buf) {
#pragma unroll
    for (int i = 0; i < 2; ++i) {
      long row = (long)t * TR + wave * 16 + i * 8 + (lane >> 3);
      if (row > (long)M - 1) row = M - 1;  // clamp (no predication on glds)
      int jc = (lane & 7) ^ (lane >> 3);
      glds16((const char*)A + row * 1024 + (size_t)s * 128 + (size_t)jc * 16,
             aw + buf * 2048 + i * 1024);
    }
  };

  stageA(blockIdx.x, 0, 0);
  stageA(blockIdx.x, 1, 1);
  __syncthreads();  // one-time full drain: B + first A chunks resident

  for (int t = blockIdx.x; t < NT; t += G) {
    f32x4 acc[NF] = {};
#pragma unroll
    for (int s = 0; s < 8; ++s) {
      // in-order FIFO per wave: [c_s(2), c_{s+1}(2), (stores at s<2)]
      if (s < 2) {
        if constexpr (STN == 8)
          asm volatile("s_waitcnt vmcnt(10)" ::: "memory");
        else
          asm volatile("s_waitcnt vmcnt(18)" ::: "memory");
      } else {
        asm volatile("s_waitcnt vmcnt(2)" ::: "memory");
      }
      const char* ab = aw + (s & 1) * 2048;
      // A fragment: row lr, k-chunk pair lj*2, lj*2+1 (XOR by row&7)
      const int sw = lr & 7;
      const int j0 = lj * 2;
      f32x4 a0 = *(const f32x4*)(ab + lr * 128 + ((j0 ^ sw) * 16));
      f32x4 a1 = *(const f32x4*)(ab + lr * 128 + (((j0 + 1) ^ sw) * 16));
      bf16x8 af;
      af[0] = (__bf16)a0[0]; af[1] = (__bf16)a0[1];
      af[2] = (__bf16)a0[2]; af[3] = (__bf16)a0[3];
      af[4] = (__bf16)a1[0]; af[5] = (__bf16)a1[1];
      af[6] = (__bf16)a1[2]; af[7] = (__bf16)a1[3];
#pragma unroll
      for (int ni = 0; ni < NF; ++ni) {
        int sl = ni * 16 + lr;
        int pc = (s * 4 + lj) ^ (sl & 7);
        bf16x8 b = __builtin_bit_cast(
            bf16x8, *(const u16x8*)((const char*)Bls + sl * 512 + pc * 16));
        acc[ni] = __builtin_amdgcn_mfma_f32_16x16x32_bf16(af, b, acc[ni],
                                                          0, 0, 0);
      }
      if (s < 6)
        stageA(t, s + 2, s & 1);
      else if (s == 6)
        stageA(t + G, 0, 0);  // next tile chunk 0 (before epilogue stores)
      else
        stageA(t + G, 1, 1);  // next tile chunk 1
    }
    // epilogue: lane writes rows wave*16+lj*4+r, cols lr*NF..lr*NF+NF-1
#pragma unroll
    for (int r = 0; r < 4; ++r) {
      long grow = (long)t * TR + wave * 16 + lj * 4 + r;
      if (grow >= M) continue;
      if (OUT_BF16) {
        bf16x8 lo, hi;
#pragma unroll
        for (int j = 0; j < 8; ++j) {
          lo[j] = (__bf16)(acc[j][r] + bv[j]);
          hi[j] = (__bf16)(acc[8 + j][r] + bv[8 + j]);
        }
        u16* pC = (u16*)Cv + grow * N + lr * NF;
        *(u16x8*)pC = __builtin_bit_cast(u16x8, lo);
        *(u16x8*)(pC + 8) = __builtin_bit_cast(u16x8, hi);
      } else {
#pragma unroll
        for (int q = 0; q < NF / 4; ++q) {
          f32x4 v;
#pragma unroll
          for (int j = 0; j < 4; ++j) v[j] = acc[q * 4 + j][r] + bv[q * 4 + j];
          *(f32x4*)((float*)Cv + grow * N + lr * NF + q * 4) = v;
        }
      }
    }
  }
}

// ---------------------------------------------------------------------------
// sample_fused v3 (unchanged from R8): XCD batch affinity + LDS precompute.
__global__ __launch_bounds__(256, 4) void sample_fused(
    const float* __restrict__ Lgo, const float* __restrict__ Lga,
    const float* __restrict__ bbox, const u16* __restrict__ vbf,
    float* __restrict__ outs) {
  const int t = threadIdx.x;
  const int bi = blockIdx.x;
  const int xcd = bi & 7;
  const int j = bi >> 3;            // 0..249
  const int half = (j >= 125) ? 1 : 0;
  const int batch = xcd + 8 * half;
  const int qb = j - 125 * half;    // 0..124
  const int i0 = (batch * 125 + qb) * 8;

  __shared__ __align__(16) float sa[8 * 128];
  __shared__ __align__(16) int4 soff[1024];
  __shared__ __align__(16) float4 sw4[1024];
  __shared__ float sb[32];
  if (t < 32) sb[t] = bbox[(size_t)i0 * 4 + t];
  ((float4*)sa)[t] = ((const float4*)(Lga + (size_t)i0 * 128))[t];
  __syncthreads();
  if (t < 64) {
    int base = (t >> 3) * 128 + (t & 7) * 16;
    float mx = -3.0e38f;
#pragma unroll
    for (int k = 0; k < 16; ++k) mx = fmaxf(mx, sa[base + k]);
    float e[16];
    float s = 0.f;
#pragma unroll
    for (int k = 0; k < 16; ++k) {
      e[k] = __expf(sa[base + k] - mx);
      s += e[k];
    }
    float inv = 1.f / s;
#pragma unroll
    for (int k = 0; k < 16; ++k) sa[base + k] = e[k] * inv;
  }
  __syncthreads();
#pragma unroll
  for (int it = 0; it < 4; ++it) {
    int idx = it * 256 + t;
    int ql = idx >> 7;
    int rest = idx & 127;
    int h = rest >> 4;
    int pt = rest & 15;
    int l = pt >> 2;
    int W = 80 >> l;
    float offx = Lgo[(size_t)(i0 + ql) * 256 + h * 32 + pt * 2];
    float offy = Lgo[(size_t)(i0 + ql) * 256 + h * 32 + pt * 2 + 1];
    float xf = (sb[ql * 4 + 0] + offx * 0.125f * sb[ql * 4 + 2]) * (float)W - 0.5f;
    float yf = (sb[ql * 4 + 1] + offy * 0.125f * sb[ql * 4 + 3]) * (float)W - 0.5f;
    float aw = sa[ql * 128 + h * 16 + pt];
    float x0f = floorf(xf), y0f = floorf(yf);
    float wx = xf - x0f, wy = yf - y0f;
    int x0 = (int)x0f, y0 = (int)y0f;
    int x1 = x0 + 1, y1 = y0 + 1;
    float fx0 = (x0 >= 0 && x0 < W) ? 1.f : 0.f;
    float fx1 = (x1 >= 0 && x1 < W) ? 1.f : 0.f;
    float fy0 = (y0 >= 0 && y0 < W) ? 1.f : 0.f;
    float fy1 = (y1 >= 0 && y1 < W) ? 1.f : 0.f;
    int xc0 = min(max(x0, 0), W - 1), xc1 = min(max(x1, 0), W - 1);
    int yc0 = min(max(y0, 0), W - 1), yc1 = min(max(y1, 0), W - 1);
    int baseb = ((25600 - (25600 >> (2 * l))) / 3) * 512;  // bytes
    int4 o;
    o.x = baseb + (yc0 * W + xc0) * 512;
    o.y = baseb + (yc0 * W + xc1) * 512;
    o.z = baseb + (yc1 * W + xc0) * 512;
    o.w = baseb + (yc1 * W + xc1) * 512;
    float aw0 = aw * (1.f - wy), aw1 = aw * wy;
    float4 wv;
    wv.x = aw0 * (1.f - wx) * fx0 * fy0;
    wv.y = aw0 * wx * fx1 * fy0;
    wv.z = aw1 * (1.f - wx) * fx0 * fy1;
    wv.w = aw1 * wx * fx1 * fy1;
    int phys = ql * 128 + h * 16 + (pt ^ h);
    soff[phys] = o;
    sw4[phys] = wv;
  }
  __syncthreads();
  const int ql = t >> 5;
  const int r = t & 31;
  const int h = r >> 2;
  const int cg = r & 3;
  const int chb = (h * 32 + cg * 8) * 2;
  const char* vbb = (const char*)vbf + (size_t)batch * 8500 * 512 + chb;
  float acc[8] = {};
#pragma unroll 2
  for (int pt = 0; pt < 16; ++pt) {
    int phys = ql * 128 + h * 16 + (pt ^ h);
    int4 o = soff[phys];
    float4 wv = sw4[phys];
    uint4 v00 = *(const uint4*)(vbb + o.x);
    uint4 v01 = *(const uint4*)(vbb + o.y);
    uint4 v10 = *(const uint4*)(vbb + o.z);
    uint4 v11 = *(const uint4*)(vbb + o.w);
    const uint32_t* p00 = (const uint32_t*)&v00;
    const uint32_t* p01 = (const uint32_t*)&v01;
    const uint32_t* p10 = (const uint32_t*)&v10;
    const uint32_t* p11 = (const uint32_t*)&v11;
#pragma unroll
    for (int k = 0; k < 4; ++k) {
      float a0 = __uint_as_float(p00[k] << 16);
      float a1 = __uint_as_float(p00[k] & 0xffff0000u);
      float b0 = __uint_as_float(p01[k] << 16);
      float b1 = __uint_as_float(p01[k] & 0xffff0000u);
      float c0 = __uint_as_float(p10[k] << 16);
      float c1 = __uint_as_float(p10[k] & 0xffff0000u);
      float d0 = __uint_as_float(p11[k] << 16);
      float d1 = __uint_as_float(p11[k] & 0xffff0000u);
      acc[2 * k] += wv.x * a0 + wv.y * b0 + wv.z * c0 + wv.w * d0;
      acc[2 * k + 1] += wv.x * a1 + wv.y * b1 + wv.z * c1 + wv.w * d1;
    }
  }
  float4* op = (float4*)(outs + (size_t)(i0 + ql) * 256 + h * 32 + cg * 8);
  op[0] = make_float4(acc[0], acc[1], acc[2], acc[3]);
  op[1] = make_float4(acc[4], acc[5], acc[6], acc[7]);
}

extern "C" void kernel_launch(void* const* d_in, const int* in_sizes, int n_in,
                              void* d_out, int out_size, void* d_ws, size_t ws_size,
                              hipStream_t stream) {
  const float* query  = (const float*)d_in[0];
  const float* bbox   = (const float*)d_in[1];
  const float* value  = (const float*)d_in[2];
  const float* W_off  = (const float*)d_in[3];
  const float* b_off  = (const float*)d_in[4];
  const float* W_attn = (const float*)d_in[5];
  const float* b_attn = (const float*)d_in[6];
  const float* W_val  = (const float*)d_in[7];
  const float* b_val  = (const float*)d_in[8];
  const float* W_out  = (const float*)d_in[9];
  const float* b_out  = (const float*)d_in[10];
  float* out = (float*)d_out;

  // workspace layout
  char* w = (char*)d_ws;
  u16* vbf     = (u16*)w;                    // 69,632,000 B
  float* Lgo   = (float*)(w + 69632000);     // 16,384,000 B
  float* Lga   = (float*)(w + 86016000);     //  8,192,000 B
  float* outs  = (float*)(w + 94208000);     // 16,384,000 B
  u16* Wt_val  = (u16*)(w + 110592000);      //    131,072 B
  u16* Wt_off  = (u16*)(w + 110723072);      //    131,072 B
  u16* Wt_attn = (u16*)(w + 110854144);      //     65,536 B
  u16* Wt_out  = (u16*)(w + 110919680);      //    131,072 B

  const int M_v = 16 * 8500;  // 136000
  const int M_q = 16 * 1000;  // 16000

  // 0) weight prep (bf16 transpose)
  wconv<<<dim3(4, 4, 4), 256, 0, stream>>>(W_val, W_off, W_attn, W_out,
                                           Wt_val, Wt_off, Wt_attn, Wt_out);
  // 1) value projection -> bf16 (persistent, 512 thr, 8 waves, 160KB LDS)
  gemm_p2<8, 16, true><<<256, 512, 0, stream>>>(
      value, Wt_val, b_val, (void*)vbf, M_v, 1063, 256);
  // 2) offset logits [16000x256]: 250 blocks x 64-row tiles
  gemm_p2<4, 16, false><<<250, 256, 0, stream>>>(
      query, Wt_off, b_off, (void*)Lgo, M_q, 250, 250);
  // 3) attn logits [16000x128]
  gemm_p2<4, 8, false><<<250, 256, 0, stream>>>(
      query, Wt_attn, b_attn, (void*)Lga, M_q, 250, 250);
  // 4) fused softmax/locs + bilinear sampling (XCD batch affinity)
  sample_fused<<<2000, 256, 0, stream>>>(Lgo, Lga, bbox, vbf, outs);
  // 5) output projection
  gemm_p2<4, 16, false><<<250, 256, 0, stream>>>(
      outs, Wt_out, b_out, (void*)out, M_q, 250, 250);
}